// Round 3
// baseline (110.639 us; speedup 1.0000x reference)
//
#include <hip/hip_runtime.h>
#include <math.h>

#define NP 4
#define NN 8192
#define NM 8192

// ws layout: mins [8 z][8192 q] floats at offset 0 (256 KB), atomicMin'd.
#define TQ 8        // queries per thread
#define QT 2048     // queries per block (256 * TQ)
#define SPLITS 64   // target-dim splits -> grid (4,64,8) = 2048 blocks = 8/CU
#define SPAN 128    // targets per block (== NN/SPLITS)
#define NPAIR (SPAN / 2)

typedef float float2v __attribute__((ext_vector_type(2)));
typedef float float4v __attribute__((ext_vector_type(4)));

__device__ inline float min3f(float a, float b, float c) {
    float d;
    asm("v_min3_f32 %0, %1, %2, %3" : "=v"(d) : "v"(a), "v"(b), "v"(c));
    return d;
}

// d.lo = fma(a.lo, b.lo, c.lo); d.hi = fma(a.lo, b.hi, c.hi)  (broadcast a.lo)
__device__ inline float2v pk_fma_blo(float2v a, float2v b, float2v c) {
    float2v d;
    asm("v_pk_fma_f32 %0, %1, %2, %3 op_sel:[0,0,0] op_sel_hi:[0,1,1]"
        : "=v"(d) : "v"(a), "v"(b), "v"(c));
    return d;
}

// d.lo = fma(a.hi, b.lo, c.lo); d.hi = fma(a.hi, b.hi, c.hi)  (broadcast a.hi)
__device__ inline float2v pk_fma_bhi(float2v a, float2v b, float2v c) {
    float2v d;
    asm("v_pk_fma_f32 %0, %1, %2, %3 op_sel:[1,0,0] op_sel_hi:[1,1,1]"
        : "=v"(d) : "v"(a), "v"(b), "v"(c));
    return d;
}

__device__ inline void make_transform(const float* __restrict__ quat,
                                      const float* __restrict__ tra,
                                      int p, float T[12]) {
    float q0 = quat[p * 4 + 0], q1 = quat[p * 4 + 1];
    float q2 = quat[p * 4 + 2], q3 = quat[p * 4 + 3];
    float inv = 1.0f / sqrtf(q0 * q0 + q1 * q1 + q2 * q2 + q3 * q3);
    float a = q0 * inv, b = q1 * inv, c = q2 * inv, d = q3 * inv;
    T[0] = 1.0f - 2.0f * c * c - 2.0f * d * d;
    T[1] = 2.0f * b * c - 2.0f * a * d;
    T[2] = 2.0f * a * c + 2.0f * b * d;
    T[3] = tra[p * 3 + 0];
    T[4] = 2.0f * b * c + 2.0f * a * d;
    T[5] = 1.0f - 2.0f * b * b - 2.0f * d * d;
    T[6] = 2.0f * c * d - 2.0f * a * b;
    T[7] = tra[p * 3 + 1];
    T[8] = 2.0f * b * d - 2.0f * a * c;
    T[9] = 2.0f * a * b + 2.0f * c * d;
    T[10] = 1.0f - 2.0f * b * b - 2.0f * c * c;
    T[11] = tra[p * 3 + 2];
}

// Fused prep+chamfer. grid (4, 64, 8) = 2048 blocks = 8 blocks/CU.
// __launch_bounds__(256,8): min 8 waves/EU -> VGPR cap 64 -> 32 waves/CU.
// Query state packed 5 VGPR/query (A={-qx,-qy}, B={-qz,h}, tmin) with
// v_pk_fma op_sel broadcasting halves -> fits the 64-VGPR budget.
// Targets staged in LDS PAIRED layout; inner: 3 pk_fma + 1 min3 per 2 pairs.
// Epilogue: fire-and-forget atomicMin into 65536-slot mins (measured free:
// round0 chamfer w/ atomics == round1 w/o, 46.1 vs 46.0 us).
__global__ __launch_bounds__(256, 8)
void chamfer_kernel(const float* __restrict__ cam, const float* __restrict__ cad,
                    const float* __restrict__ quat, const float* __restrict__ tra,
                    float* __restrict__ mins_f, float* __restrict__ out) {
    int tid = threadIdx.x;
    int p = blockIdx.z >> 1;
    int role = blockIdx.z & 1;

    float T[12];
    make_transform(quat, tra, p, T);

    if (blockIdx.x == 0 && blockIdx.y == 0 && blockIdx.z == 0) {
        if (tid < 64) {
            int p2 = tid >> 4;
            int r = (tid >> 2) & 3;
            int c = tid & 3;
            float T2[12];
            make_transform(quat, tra, p2, T2);
            float v;
            if (r == 3)
                v = (c == 3) ? 1.0f : 0.0f;
            else
                v = T2[r * 4 + c];
            out[1 + tid] = v;
        } else if (tid == 64) {
            out[0] = 0.0f;
        }
    }

    // ---- stage SPAN targets into LDS (paired layout), transform if cad ----
    // role==0: queries = cad_t, targets = cam ; role==1: queries = cam, targets = cad_t
    __shared__ float sQf[SPAN * 4];  // 2 KB
    if (tid < SPAN) {
        const float* src = (role ? cad : cam) +
                           ((size_t)p * 8192 + blockIdx.y * SPAN + tid) * 3;
        float x = src[0], y = src[1], z = src[2];
        float vx, vy, vz;
        if (role) {
            vx = fmaf(T[0], x, fmaf(T[1], y, fmaf(T[2], z, T[3])));
            vy = fmaf(T[4], x, fmaf(T[5], y, fmaf(T[6], z, T[7])));
            vz = fmaf(T[8], x, fmaf(T[9], y, fmaf(T[10], z, T[11])));
        } else {
            vx = x; vy = y; vz = z;
        }
        float h = 0.5f * (vx * vx + vy * vy + vz * vz);
        int lane = tid & 1;
        int f = (tid & ~1) * 4;  // pair pp: quad 2pp={x0,x1,y0,y1}, 2pp+1={z0,z1,h0,h1}
        sQf[f + lane] = vx;
        sQf[f + 2 + lane] = vy;
        sQf[f + 4 + lane] = vz;
        sQf[f + 6 + lane] = h;
    }

    // ---- load + transform TQ queries per thread ----
    const float INF = __uint_as_float(0x7f800000u);
    int q0 = blockIdx.x * QT + tid;
    const float* qbase = (role ? cam : cad) + (size_t)p * 8192 * 3;
    float2v A[TQ], B[TQ];
    float tmin[TQ];
#pragma unroll
    for (int k = 0; k < TQ; ++k) {
        const float* s = qbase + (size_t)(q0 + k * 256) * 3;
        float x = s[0], y = s[1], z = s[2];
        float vx, vy, vz;
        if (!role) {
            vx = fmaf(T[0], x, fmaf(T[1], y, fmaf(T[2], z, T[3])));
            vy = fmaf(T[4], x, fmaf(T[5], y, fmaf(T[6], z, T[7])));
            vz = fmaf(T[8], x, fmaf(T[9], y, fmaf(T[10], z, T[11])));
        } else {
            vx = x; vy = y; vz = z;
        }
        float h = 0.5f * (vx * vx + vy * vy + vz * vz);
        A[k] = (float2v){-vx, -vy};
        B[k] = (float2v){-vz, h};
        tmin[k] = INF;
    }
    __syncthreads();

    const float4v* sQd = (const float4v*)sQf;
    float4v xy0 = sQd[0], zh0 = sQd[1];
#pragma unroll 2
    for (int pp = 0; pp < NPAIR; ++pp) {
        int pn = (pp + 1) & (NPAIR - 1);  // last iter reloads pair 0
        float4v xy1 = sQd[2 * pn];
        float4v zh1 = sQd[2 * pn + 1];

        float2v X = __builtin_shufflevector(xy0, xy0, 0, 1);
        float2v Y = __builtin_shufflevector(xy0, xy0, 2, 3);
        float2v Z = __builtin_shufflevector(zh0, zh0, 0, 1);
        float2v H = __builtin_shufflevector(zh0, zh0, 2, 3);
#pragma unroll
        for (int k = 0; k < TQ; ++k) {
            float2v t = pk_fma_blo(B[k], Z, H);   // -qz*Z + H
            t = pk_fma_bhi(A[k], Y, t);           // -qy*Y + ...
            t = pk_fma_blo(A[k], X, t);           // -qx*X + ...
            tmin[k] = min3f(tmin[k], t.x, t.y);
        }
        xy0 = xy1;
        zh0 = zh1;
    }

    unsigned int* mins = (unsigned int*)mins_f + (size_t)blockIdx.z * 8192;
#pragma unroll
    for (int k = 0; k < TQ; ++k) {
        float d2 = 2.0f * (B[k].y + tmin[k]);
        d2 = fmaxf(d2, 0.0f);
        atomicMin(&mins[q0 + k * 256], __float_as_uint(d2));
    }
}

// 256 blocks x 256 threads: one (z, q) item per thread over the 256 KB mins
// array, then sqrt, weight, hierarchical sum into out[0].
__global__ __launch_bounds__(256) void finalize_kernel(
    const float* __restrict__ mins, const float* __restrict__ w,
    float* __restrict__ out) {
    int i = blockIdx.x * 256 + threadIdx.x;  // [0, 65536)
    int tid = threadIdx.x;

    float m = mins[i];
    float acc = w[i >> 14] * sqrtf(m);  // p = (i>>13)>>1

#pragma unroll
    for (int off = 32; off > 0; off >>= 1) acc += __shfl_down(acc, off, 64);

    __shared__ float wsum[4];
    if ((tid & 63) == 0) wsum[tid >> 6] = acc;
    __syncthreads();
    if (tid == 0) {
        float blocksum = (wsum[0] + wsum[1] + wsum[2] + wsum[3]) * (1.0f / 8192.0f);
        atomicAdd(out, blocksum);
    }
}

extern "C" void kernel_launch(void* const* d_in, const int* in_sizes, int n_in,
                              void* d_out, int out_size, void* d_ws, size_t ws_size,
                              hipStream_t stream) {
    const float* cam = (const float*)d_in[0];   // (P, N, 3)
    const float* cad = (const float*)d_in[1];   // (P, M, 3)
    const float* w = (const float*)d_in[2];     // (P,)
    const float* quat = (const float*)d_in[3];  // (P, 4)
    const float* tra = (const float*)d_in[4];   // (P, 3, 1)
    float* out = (float*)d_out;
    float* ws = (float*)d_ws;

    // Poison mins with 0x7f7f7f7f (= 4.3e38, > any real distance^2).
    hipMemsetAsync(ws, 0x7f, (size_t)65536 * sizeof(float), stream);

    dim3 grid(NM / QT, SPLITS, 2 * NP);
    chamfer_kernel<<<grid, 256, 0, stream>>>(cam, cad, quat, tra, ws, out);

    finalize_kernel<<<256, 256, 0, stream>>>(ws, w, out);
}